// Round 7
// baseline (114.432 us; speedup 1.0000x reference)
//
#include <hip/hip_runtime.h>

// LinkPredictor: out[e] = W2 . relu(W1s.z[src] + W1d.z[dst] + b1) + b2
// Factored: C = z @ [W1s|W1d]^T  (node GEMM, bf16 MFMA), then per-edge
// gather + fused add/relu/dot.
// GEMM v7: B staged ONCE in LDS (64 KB swizzled, the only LDS); A loaded
// global->VGPR with a 4-buffer static rotation (3-chunk prefetch depth,
// sched_barrier-pinned); 512-thread blocks -> 2 waves/SIMD; one barrier.

#define NN 100000   // nodes
#define NE 300000   // edges
#define KD 256      // in channels (K)
#define NO 512      // 2*HID output cols (A | B)
#define BN 128      // cols per block
#define NSLOT 3125  // 100000 / 32 rows per slot (exact)
#define NSTRM 512   // wave streams per nt-column

typedef __attribute__((ext_vector_type(8))) short short8;
typedef __attribute__((ext_vector_type(8))) unsigned short ushort8;
typedef __attribute__((ext_vector_type(4))) float f32x4;
typedef __attribute__((ext_vector_type(4))) unsigned int uint4v;

__device__ __forceinline__ unsigned short f2bf(float f) {
  union { float f; unsigned int u; } v; v.f = f;
  unsigned int u = v.u;
  u += 0x7fffu + ((u >> 16) & 1u);   // RNE
  return (unsigned short)(u >> 16);
}
__device__ __forceinline__ float bf2f(unsigned short h) {
  union { unsigned int u; float f; } v; v.u = ((unsigned int)h) << 16;
  return v.f;
}
// pack 2 f32 -> {bf16(a) low, bf16(b) high} (round-half-up)
__device__ __forceinline__ unsigned int pkbf(float a, float b) {
  unsigned int ua = __float_as_uint(a) + 0x8000u;
  unsigned int ub = __float_as_uint(b) + 0x8000u;
  return __builtin_amdgcn_perm(ub, ua, 0x07060302u);
}
// stored-col -> hidden-channel permutation (within 0..255)
__device__ __forceinline__ int hperm(int s) {
  int j = s & 127;
  return (s & ~127) + ((j & 7) << 4) + (j >> 3);
}

// ---- repack W1 (f32 [256][512]) -> Wt (bf16 [512][256], K-contiguous) ----
__global__ void prep_w(const float* __restrict__ W1, unsigned short* __restrict__ Wt) {
  int idx = blockIdx.x * 256 + threadIdx.x;   // 512*256 = 131072
  int j = idx >> 8, k = idx & 255;
  float v = (j < 256) ? W1[j * 512 + k] : W1[(j - 256) * 512 + 256 + k];
  Wt[idx] = f2bf(v);
}

// ---- C[n][perm(j)] = sum_k z[n][k] * Wt[j][k] ----
__global__ __launch_bounds__(512, 2) void gemm_zw(const float* __restrict__ z,
                                                  const unsigned short* __restrict__ Wt,
                                                  unsigned short* __restrict__ C) {
  __shared__ unsigned short Bs[BN * KD];   // 64 KB (the only LDS)

  // XCD-pinned: nt-siblings of one m-group share blockIdx&7 (same XCD)
  const int b = blockIdx.x;            // 0..255
  const int xcd = b & 7;
  const int q = b >> 3;                // 0..31
  const int nt = q & 3;
  const int mgrp = xcd * 8 + (q >> 2); // 0..63
  const int n0 = nt * BN;

  const int t = threadIdx.x;           // 0..511
  const int w = t >> 6, lane = t & 63;
  const int l15 = lane & 15, l4 = lane >> 4;

  // ---- stage B once: Bs[row][chunk c stored at c^(row&7)], coalesced src
#pragma unroll
  for (int i = 0; i < 8; ++i) {
    const int id = t + 512 * i;        // 0..4095 16B-chunks
    const int row = id >> 5, c = id & 31;
    ushort8 v = *(const ushort8*)(Wt + (size_t)(n0 + row) * KD + c * 8);
    *(ushort8*)&Bs[row * KD + ((c ^ (row & 7)) << 3)] = v;
  }
  __syncthreads();                     // the ONLY barrier

  const int strm = mgrp * 8 + w;       // 0..511 independent wave streams

#define LOADC(c, PA, PB, PC, PD)                                   \
  PA = *(const float4*)(zr + (c) * 32);                            \
  PB = *(const float4*)(zr + (c) * 32 + 4);                        \
  PC = *(const float4*)(zr + 16 * KD + (c) * 32);                  \
  PD = *(const float4*)(zr + 16 * KD + (c) * 32 + 4);              \
  __builtin_amdgcn_sched_barrier(0);

#define COMPUTE(c, PA, PB, PC, PD)                                 \
  {                                                                \
    union { uint4v u; short8 s; } a0v, a1v;                        \
    a0v.u[0] = pkbf(PA.x, PA.y); a0v.u[1] = pkbf(PA.z, PA.w);      \
    a0v.u[2] = pkbf(PB.x, PB.y); a0v.u[3] = pkbf(PB.z, PB.w);      \
    a1v.u[0] = pkbf(PC.x, PC.y); a1v.u[1] = pkbf(PC.z, PC.w);      \
    a1v.u[2] = pkbf(PD.x, PD.y); a1v.u[3] = pkbf(PD.z, PD.w);      \
    const int kc = (c) * 4 + l4;                                   \
    _Pragma("unroll")                                              \
    for (int n = 0; n < 8; ++n) {                                  \
      union { ushort8 u; short8 s; } bv;                           \
      bv.u = *(const ushort8*)&Bs[(n * 16 + l15) * KD +            \
                                  ((kc ^ (l15 & 7)) << 3)];        \
      acc0[n] = __builtin_amdgcn_mfma_f32_16x16x32_bf16(a0v.s, bv.s, acc0[n], 0, 0, 0); \
      acc1[n] = __builtin_amdgcn_mfma_f32_16x16x32_bf16(a1v.s, bv.s, acc1[n], 0, 0, 0); \
    }                                                              \
  }

  for (int s = strm; s < NSLOT; s += NSTRM) {
    // band0 row = s*32 + l15, band1 = +16; lane's K-offset l4*8
    const float* zr = z + ((size_t)s * 32 + l15) * KD + l4 * 8;

    float4 P0a, P0b, P0c, P0d, P1a, P1b, P1c, P1d;
    float4 P2a, P2b, P2c, P2d, P3a, P3b, P3c, P3d;

    LOADC(0, P0a, P0b, P0c, P0d)
    LOADC(1, P1a, P1b, P1c, P1d)
    LOADC(2, P2a, P2b, P2c, P2d)

    f32x4 acc0[8], acc1[8];
#pragma unroll
    for (int n = 0; n < 8; ++n) { acc0[n] = (f32x4)0.f; acc1[n] = (f32x4)0.f; }

    LOADC(3, P3a, P3b, P3c, P3d)
    COMPUTE(0, P0a, P0b, P0c, P0d)
    LOADC(4, P0a, P0b, P0c, P0d)
    COMPUTE(1, P1a, P1b, P1c, P1d)
    LOADC(5, P1a, P1b, P1c, P1d)
    COMPUTE(2, P2a, P2b, P2c, P2d)
    LOADC(6, P2a, P2b, P2c, P2d)
    COMPUTE(3, P3a, P3b, P3c, P3d)
    LOADC(7, P3a, P3b, P3c, P3d)
    COMPUTE(4, P0a, P0b, P0c, P0d)
    COMPUTE(5, P1a, P1b, P1c, P1d)
    COMPUTE(6, P2a, P2b, P2c, P2d)
    COMPUTE(7, P3a, P3b, P3c, P3d)

    // epilogue: one 16B store per lane per row, permuted cols j = l15*8+n
#pragma unroll
    for (int r = 0; r < 4; ++r) {
      uint4v p;
      p[0] = pkbf(acc0[0][r], acc0[1][r]); p[1] = pkbf(acc0[2][r], acc0[3][r]);
      p[2] = pkbf(acc0[4][r], acc0[5][r]); p[3] = pkbf(acc0[6][r], acc0[7][r]);
      *(uint4v*)(C + ((size_t)s * 32 + l4 * 4 + r) * NO + n0 + l15 * 8) = p;
      p[0] = pkbf(acc1[0][r], acc1[1][r]); p[1] = pkbf(acc1[2][r], acc1[3][r]);
      p[2] = pkbf(acc1[4][r], acc1[5][r]); p[3] = pkbf(acc1[6][r], acc1[7][r]);
      *(uint4v*)(C + ((size_t)s * 32 + 16 + l4 * 4 + r) * NO + n0 + l15 * 8) = p;
    }
  }
#undef LOADC
#undef COMPUTE
}

// ---- per-edge: out[e] = b2 + sum W2[h]*relu(A[s][h] + B[d][h] + b1[h]) ----
// C cols are permuted; load b1/W2 through hperm to match.
__global__ __launch_bounds__(256) void edge_mlp(const unsigned short* __restrict__ C,
                                                const int* __restrict__ ei,
                                                const float* __restrict__ b1,
                                                const float* __restrict__ W2,
                                                const float* __restrict__ b2,
                                                float* __restrict__ out) {
  const int t = threadIdx.x;
  const int lane = t & 63;
  const int g = lane >> 4;           // edge slot within wave (0..3)
  const int c0 = (lane & 15) * 16;   // stored-channel base for this lane
  float b1v[16], w2v[16];
#pragma unroll
  for (int i = 0; i < 16; ++i) {
    const int h = hperm(c0 + i);
    b1v[i] = b1[h]; w2v[i] = W2[h];
  }
  const float bias2 = b2[0];
  const int waveId = blockIdx.x * 4 + (t >> 6);
  const int nw = gridDim.x * 4;
  for (int e0 = waveId * 4; e0 < NE; e0 += nw * 4) {
    const int e = e0 + g;                 // NE % 4 == 0 -> always valid
    const int sn = ei[e];
    const int dn = ei[NE + e];
    const ushort8* ap = (const ushort8*)(C + (size_t)sn * NO + c0);
    const ushort8* bp = (const ushort8*)(C + (size_t)dn * NO + 256 + c0);
    ushort8 a0 = ap[0], a1 = ap[1];
    ushort8 v0 = bp[0], v1 = bp[1];
    float partial = 0.f;
#pragma unroll
    for (int j = 0; j < 8; ++j) {
      float h = bf2f(a0[j]) + bf2f(v0[j]) + b1v[j];
      h = fmaxf(h, 0.f);
      partial = fmaf(h, w2v[j], partial);
    }
#pragma unroll
    for (int j = 0; j < 8; ++j) {
      float h = bf2f(a1[j]) + bf2f(v1[j]) + b1v[8 + j];
      h = fmaxf(h, 0.f);
      partial = fmaf(h, w2v[8 + j], partial);
    }
    partial += __shfl_xor(partial, 8);
    partial += __shfl_xor(partial, 4);
    partial += __shfl_xor(partial, 2);
    partial += __shfl_xor(partial, 1);
    if ((lane & 15) == 0) out[e] = partial + bias2;
  }
}

extern "C" void kernel_launch(void* const* d_in, const int* in_sizes, int n_in,
                              void* d_out, int out_size, void* d_ws, size_t ws_size,
                              hipStream_t stream) {
  const float* z  = (const float*)d_in[0];
  const float* W1 = (const float*)d_in[1];
  const float* b1 = (const float*)d_in[2];
  const float* W2 = (const float*)d_in[3];
  const float* b2 = (const float*)d_in[4];
  const int*   ei = (const int*)d_in[5];
  float* out = (float*)d_out;

  unsigned short* C  = (unsigned short*)d_ws;          // 100000*512 bf16 = 102.4 MB
  unsigned short* Wt = C + (size_t)NN * NO;            // 512*256 bf16 = 256 KB

  prep_w<<<512, 256, 0, stream>>>(W1, Wt);
  gemm_zw<<<256, 512, 0, stream>>>(z, Wt, C);
  edge_mlp<<<2048, 256, 0, stream>>>(C, ei, b1, W2, b2, out);
}